// Round 3
// baseline (588.819 us; speedup 1.0000x reference)
//
#include <hip/hip_runtime.h>
#include <hip/hip_bf16.h>
#include <cstdint>
#include <climits>

// Problem constants (fixed by reference): B=2, T=4096, D=512, H=8, hd=64, W=16
#define TT 4096
#define DD 512
#define HH 8
#define HD 64
#define WW 16
#define CANTOR_DEPTH 8

// ---------------- Routes via c-value buckets ----------------
// c[t] = m/256 where m packs the 8 (digit==2) bits. Distances |c_t-c_s| are
// exact fp32 multiples of 1/256, so fp32 top-k order == integer |m_t-m_s| order.
// Softmax+PV are symmetric in w, so only the SET of 16 matters; ties at the
// cutoff distance go to lowest index (stable top_k). Each block rebuilds the
// bucket lists in LDS (cheap, parallel) and handles 256 t's.
__global__ __launch_bounds__(256) void routes_bucket_kernel(int* __restrict__ routes) {
    __shared__ int kv[TT];       // c-value index (0..255) per position
    __shared__ int blist[TT];    // positions grouped by value, index-ascending
    __shared__ int cnt[256];
    __shared__ int start[256];

    const int tid = threadIdx.x;

    // 1. bit-exact cantor digits -> integer value (same fp32 op sequence as ref)
    for (int t = tid; t < TT; t += 256) {
        float x = (float)t / (float)(TT - 1);
        x = fminf(fmaxf(x, 1e-6f), 1.0f - 1e-6f);
        int m = 0;
        #pragma unroll
        for (int i = 0; i < CANTOR_DEPTH; ++i) {
            float x3 = x * 3.0f;
            float dg = floorf(x3);
            x = x3 - dg;
            m = (m << 1) | ((dg == 2.0f) ? 1 : 0);
        }
        kv[t] = m;
    }
    if (tid < 256) cnt[tid] = 0;
    __syncthreads();
    for (int t = tid; t < TT; t += 256) atomicAdd(&cnt[kv[t]], 1);
    __syncthreads();
    if (tid == 0) {
        int s = 0;
        for (int v = 0; v < 256; ++v) { start[v] = s; s += cnt[v]; }
    }
    __syncthreads();
    // 2. bucket fill, index order (thread v scans all t; kv[t] read is LDS broadcast)
    {
        int o = start[tid];
        for (int t = 0; t < TT; ++t)
            if (kv[t] == tid) blist[o++] = t;
    }
    __syncthreads();

    // 3. per-t selection
    const int t = blockIdx.x * 256 + tid;
    const int kt = kv[t];
    int* __restrict__ rt = &routes[t * WW];
    int n = 0;
    // d = 0
    {
        int c = cnt[kt], s0 = start[kt];
        int take = (c < WW) ? c : WW;
        for (int i = 0; i < take; ++i) rt[n++] = blist[s0 + i];
    }
    for (int d = 1; n < WW && d <= 256; ++d) {
        const int lo = kt - d, hi = kt + d;
        const int clo = (lo >= 0) ? cnt[lo] : 0;
        const int chi = (hi < 256) ? cnt[hi] : 0;
        const int slo = (lo >= 0) ? start[lo] : 0;
        const int shi = (hi < 256) ? start[hi] : 0;
        const int need = WW - n;
        if (clo + chi <= need) {
            for (int i = 0; i < clo; ++i) rt[n++] = blist[slo + i];
            for (int i = 0; i < chi; ++i) rt[n++] = blist[shi + i];
        } else {
            // merge by ascending index, take `need` smallest
            int i = 0, j = 0;
            while (n < WW) {
                int a = (i < clo) ? blist[slo + i] : INT_MAX;
                int b = (j < chi) ? blist[shi + j] : INT_MAX;
                if (a < b) { rt[n++] = a; ++i; }
                else       { rt[n++] = b; ++j; }
            }
        }
    }
}

// ---------------- fp32 GEMM + bias: C[M,N] = A[M,K]@W[K,N] + b ----------------
// 128x128 block tile, BK=16, 8x8 per-thread (cols split tx*4 / 64+tx*4 to keep
// LDS reads <=2-way).
#define BM 128
#define BN 128
#define BK 16
#define LDP (BM + 4)   // padded row stride (132 floats = 528 B, 16B-aligned)

__global__ __launch_bounds__(256) void gemm_bias_v2(const float* __restrict__ A,
                                                    const float* __restrict__ W,
                                                    const float* __restrict__ bias,
                                                    float* __restrict__ C,
                                                    int M, int N, int K) {
    __shared__ float As[BK][LDP];   // [k][m]
    __shared__ float Ws[BK][LDP];   // [k][n]

    const int tid = threadIdx.x;
    const int tx = tid & 15;        // n groups
    const int ty = tid >> 4;        // m: 8 consecutive rows
    const int bn = blockIdx.x * BN;
    const int bm = blockIdx.y * BM;

    float acc[8][8] = {};

    for (int k0 = 0; k0 < K; k0 += BK) {
        // A tile: 128 rows x 16 k. thread: row tid>>1, k-offset (tid&1)*8, 8 floats, transposed store
        {
            const int r  = tid >> 1;
            const int kq = (tid & 1) * 8;
            const float* src = &A[(size_t)(bm + r) * K + k0 + kq];
            const float4 v0 = *reinterpret_cast<const float4*>(src);
            const float4 v1 = *reinterpret_cast<const float4*>(src + 4);
            As[kq + 0][r] = v0.x; As[kq + 1][r] = v0.y; As[kq + 2][r] = v0.z; As[kq + 3][r] = v0.w;
            As[kq + 4][r] = v1.x; As[kq + 5][r] = v1.y; As[kq + 6][r] = v1.z; As[kq + 7][r] = v1.w;
        }
        // W tile: 16 rows x 128 n, two float4 per thread
        {
            const int wk = tid >> 4;
            const int wn = (tid & 15) * 4;
            const float* src = &W[(size_t)(k0 + wk) * N + bn];
            *reinterpret_cast<float4*>(&Ws[wk][wn])      = *reinterpret_cast<const float4*>(src + wn);
            *reinterpret_cast<float4*>(&Ws[wk][wn + 64]) = *reinterpret_cast<const float4*>(src + wn + 64);
        }
        __syncthreads();
        #pragma unroll
        for (int kk = 0; kk < BK; ++kk) {
            const float4 a0 = *reinterpret_cast<const float4*>(&As[kk][ty * 8]);
            const float4 a1 = *reinterpret_cast<const float4*>(&As[kk][ty * 8 + 4]);
            const float4 w0 = *reinterpret_cast<const float4*>(&Ws[kk][tx * 4]);
            const float4 w1 = *reinterpret_cast<const float4*>(&Ws[kk][tx * 4 + 64]);
            const float a[8] = {a0.x, a0.y, a0.z, a0.w, a1.x, a1.y, a1.z, a1.w};
            const float w[8] = {w0.x, w0.y, w0.z, w0.w, w1.x, w1.y, w1.z, w1.w};
            #pragma unroll
            for (int i = 0; i < 8; ++i)
                #pragma unroll
                for (int j = 0; j < 8; ++j)
                    acc[i][j] += a[i] * w[j];
        }
        __syncthreads();
    }

    const float4 b0 = *reinterpret_cast<const float4*>(&bias[bn + tx * 4]);
    const float4 b1 = *reinterpret_cast<const float4*>(&bias[bn + tx * 4 + 64]);
    #pragma unroll
    for (int i = 0; i < 8; ++i) {
        float* dst = &C[(size_t)(bm + ty * 8 + i) * N + bn];
        float4 o0, o1;
        o0.x = acc[i][0] + b0.x; o0.y = acc[i][1] + b0.y; o0.z = acc[i][2] + b0.z; o0.w = acc[i][3] + b0.w;
        o1.x = acc[i][4] + b1.x; o1.y = acc[i][5] + b1.y; o1.z = acc[i][6] + b1.z; o1.w = acc[i][7] + b1.w;
        *reinterpret_cast<float4*>(dst + tx * 4)      = o0;
        *reinterpret_cast<float4*>(dst + tx * 4 + 64) = o1;
    }
}

// ---------------- Windowed attention, one wave per (b,h,t) ----------------
__global__ __launch_bounds__(256) void attn_kernel(const float* __restrict__ Q,
                                                   const float* __restrict__ K,
                                                   const float* __restrict__ V,
                                                   const int* __restrict__ routes,
                                                   const float* __restrict__ temp_ptr,
                                                   float* __restrict__ O, int B) {
    const int lane = threadIdx.x & 63;
    const int u = (blockIdx.x * blockDim.x + threadIdx.x) >> 6;  // (b*H+h)*T + t
    const int total = B * HH * TT;
    if (u >= total) return;
    const int t = u & (TT - 1);
    const int bh = u >> 12;
    const int h = bh & (HH - 1);
    const int b = bh >> 3;

    const float scale_inv = 1.0f / (8.0f * fabsf(temp_ptr[0]));  // sqrt(64)=8

    const size_t base = ((size_t)(b * TT + t)) * DD + h * HD + lane;
    const float q = Q[base];

    const int* rt = &routes[t * WW];
    int sidx[WW];
    #pragma unroll
    for (int w = 0; w < WW; ++w) sidx[w] = rt[w];

    float sc[WW];
    #pragma unroll
    for (int w = 0; w < WW; ++w) {
        const size_t koff = ((size_t)(b * TT + sidx[w])) * DD + h * HD + lane;
        float prod = q * K[koff];
        #pragma unroll
        for (int off = 32; off > 0; off >>= 1) prod += __shfl_xor(prod, off, 64);
        sc[w] = prod * scale_inv;
    }

    float m = sc[0];
    #pragma unroll
    for (int w = 1; w < WW; ++w) m = fmaxf(m, sc[w]);
    float p[WW];
    float sum = 0.0f;
    #pragma unroll
    for (int w = 0; w < WW; ++w) { p[w] = expf(sc[w] - m); sum += p[w]; }
    const float inv = 1.0f / sum;

    float o = 0.0f;
    #pragma unroll
    for (int w = 0; w < WW; ++w) {
        const size_t voff = ((size_t)(b * TT + sidx[w])) * DD + h * HD + lane;
        o += p[w] * V[voff];
    }
    O[base] = o * inv;
}

// ---------------- Launcher ----------------
extern "C" void kernel_launch(void* const* d_in, const int* in_sizes, int n_in,
                              void* d_out, int out_size, void* d_ws, size_t ws_size,
                              hipStream_t stream) {
    const float* x    = (const float*)d_in[0];
    const float* Wq   = (const float*)d_in[1];
    const float* bq   = (const float*)d_in[2];
    const float* Wk   = (const float*)d_in[3];
    const float* bk   = (const float*)d_in[4];
    const float* Wv   = (const float*)d_in[5];
    const float* bv   = (const float*)d_in[6];
    const float* Wo   = (const float*)d_in[7];
    const float* bo   = (const float*)d_in[8];
    const float* temp = (const float*)d_in[9];
    float* out = (float*)d_out;

    const int B = in_sizes[0] / (TT * DD);   // 2
    const int M = B * TT;                    // 8192

    // workspace layout (fp32)
    float* Qb = (float*)d_ws;
    float* Kb = Qb + (size_t)M * DD;
    float* Vb = Kb + (size_t)M * DD;
    float* AO = Vb + (size_t)M * DD;
    int* routes = (int*)(AO + (size_t)M * DD);

    routes_bucket_kernel<<<TT / 256, 256, 0, stream>>>(routes);

    dim3 ggrid(DD / BN, M / BM);
    gemm_bias_v2<<<ggrid, 256, 0, stream>>>(x, Wq, bq, Qb, M, DD, DD);
    gemm_bias_v2<<<ggrid, 256, 0, stream>>>(x, Wk, bk, Kb, M, DD, DD);
    gemm_bias_v2<<<ggrid, 256, 0, stream>>>(x, Wv, bv, Vb, M, DD, DD);

    const int waves = B * HH * TT;                 // 65536
    attn_kernel<<<(waves * 64) / 256, 256, 0, stream>>>(Qb, Kb, Vb, routes, temp, AO, B);

    gemm_bias_v2<<<ggrid, 256, 0, stream>>>(AO, Wo, bo, out, M, DD, DD);
}

// Round 5
// 480.438 us; speedup vs baseline: 1.2256x; 1.2256x over previous
//
#include <hip/hip_runtime.h>
#include <hip/hip_bf16.h>
#include <cstdint>
#include <climits>

#define TT 4096
#define DD 512
#define HH 8
#define HD 64
#define WW 16
#define CDEPTH 8

typedef unsigned short ushortT;
typedef unsigned int uintT;
using bf16x8 = __attribute__((ext_vector_type(8))) short;
using f32x4  = __attribute__((ext_vector_type(4))) float;

static __device__ __forceinline__ uintT f2bf(float v) {
    __hip_bfloat16 h = __float2bfloat16(v);
    return (uintT)*reinterpret_cast<ushortT*>(&h);
}
static __device__ __forceinline__ float bf2f(uintT u) {
    return __uint_as_float(u << 16);
}

// ---------------- Routes table: one 16-list per c-value (256 values) ----------------
// c = m/256 exactly; fp32 distance order == |m_t-m_s| integer order. Equal-c rows are
// identical => routes depend only on m. Whole rings ascending; cutoff ring merged by
// ascending index (stable top_k). Validated by round-3 pass.
__global__ __launch_bounds__(256) void routes_table_kernel(int* __restrict__ kv_g,
                                                           int* __restrict__ table) {
    __shared__ int kv[TT];
    __shared__ int cnt[256];
    __shared__ int f16[256][16];
    const int tid = threadIdx.x;

    for (int t = tid; t < TT; t += 256) {
        float x = (float)t / (float)(TT - 1);
        x = fminf(fmaxf(x, 1e-6f), 1.0f - 1e-6f);
        int m = 0;
        #pragma unroll
        for (int i = 0; i < CDEPTH; ++i) {
            float x3 = x * 3.0f;
            float dg = floorf(x3);
            x = x3 - dg;
            m = (m << 1) | ((dg == 2.0f) ? 1 : 0);
        }
        kv[t] = m;
        kv_g[t] = m;
    }
    cnt[tid] = 0;
    __syncthreads();
    for (int t = tid; t < TT; t += 256) atomicAdd(&cnt[kv[t]], 1);
    __syncthreads();

    int nf = 0;
    for (int t0 = 0; t0 < TT; t0 += 8) {
        #pragma unroll
        for (int j = 0; j < 8; ++j) {
            int val = kv[t0 + j];
            if (val == tid && nf < 16) { f16[tid][nf] = t0 + j; ++nf; }
        }
    }
    __syncthreads();

    int* rt = &table[tid * WW];
    int n = 0;
    {
        int c = cnt[tid];
        int take = (c < WW) ? c : WW;
        for (int i = 0; i < take; ++i) rt[n++] = f16[tid][i];
    }
    for (int d = 1; n < WW && d <= 256; ++d) {
        const int lo = tid - d, hi = tid + d;
        const int clo = (lo >= 0) ? cnt[lo] : 0;
        const int chi = (hi < 256) ? cnt[hi] : 0;
        const int need = WW - n;
        if (clo + chi <= need) {
            for (int i = 0; i < clo; ++i) rt[n++] = f16[lo][i];
            for (int i = 0; i < chi; ++i) rt[n++] = f16[hi][i];
        } else {
            const int cl = (clo < WW) ? clo : WW;
            const int ch = (chi < WW) ? chi : WW;
            int i = 0, j = 0;
            while (n < WW) {
                int a = (i < cl) ? f16[lo][i] : INT_MAX;
                int b = (j < ch) ? f16[hi][j] : INT_MAX;
                if (a < b) { rt[n++] = a; ++i; }
                else       { rt[n++] = b; ++j; }
            }
        }
    }
}

// ---------------- x -> bf16 hi/lo split ----------------
__global__ void convx_split_kernel(const float* __restrict__ in,
                                   ushortT* __restrict__ hi, ushortT* __restrict__ lo, int n8) {
    int i = blockIdx.x * blockDim.x + threadIdx.x;
    if (i >= n8) return;
    const float4 v0 = reinterpret_cast<const float4*>(in)[i * 2];
    const float4 v1 = reinterpret_cast<const float4*>(in)[i * 2 + 1];
    float v[8] = {v0.x, v0.y, v0.z, v0.w, v1.x, v1.y, v1.z, v1.w};
    uintT rh[8], rl[8];
    #pragma unroll
    for (int j = 0; j < 8; ++j) {
        uintT h = f2bf(v[j]);
        rh[j] = h;
        rl[j] = f2bf(v[j] - bf2f(h));
    }
    uint4 oh, ol;
    oh.x = rh[0] | (rh[1] << 16); oh.y = rh[2] | (rh[3] << 16);
    oh.z = rh[4] | (rh[5] << 16); oh.w = rh[6] | (rh[7] << 16);
    ol.x = rl[0] | (rl[1] << 16); ol.y = rl[2] | (rl[3] << 16);
    ol.z = rl[4] | (rl[5] << 16); ol.w = rl[6] | (rl[7] << 16);
    reinterpret_cast<uint4*>(hi)[i] = oh;
    reinterpret_cast<uint4*>(lo)[i] = ol;
}

// ---------------- W[k][n] -> Wt[n][k] bf16 hi/lo (4 weights) ----------------
__global__ __launch_bounds__(256) void convw_split_kernel(
        const float* __restrict__ W0, const float* __restrict__ W1,
        const float* __restrict__ W2, const float* __restrict__ W3,
        ushortT* __restrict__ H0, ushortT* __restrict__ L0,
        ushortT* __restrict__ H1, ushortT* __restrict__ L1,
        ushortT* __restrict__ H2, ushortT* __restrict__ L2,
        ushortT* __restrict__ H3, ushortT* __restrict__ L3) {
    const float* src; ushortT* dh; ushortT* dl;
    switch (blockIdx.z) {
        case 0: src = W0; dh = H0; dl = L0; break;
        case 1: src = W1; dh = H1; dl = L1; break;
        case 2: src = W2; dh = H2; dl = L2; break;
        default: src = W3; dh = H3; dl = L3; break;
    }
    __shared__ float tile[32][33];
    const int k0 = blockIdx.y * 32, n0 = blockIdx.x * 32;
    const int ty = threadIdx.x >> 3;
    const int tx = (threadIdx.x & 7) * 4;
    const float4 v = *reinterpret_cast<const float4*>(&src[(size_t)(k0 + ty) * DD + n0 + tx]);
    tile[ty][tx + 0] = v.x; tile[ty][tx + 1] = v.y; tile[ty][tx + 2] = v.z; tile[ty][tx + 3] = v.w;
    __syncthreads();
    uintT rh[4], rl[4];
    #pragma unroll
    for (int j = 0; j < 4; ++j) {
        float f = tile[tx + j][ty];
        uintT h = f2bf(f);
        rh[j] = h;
        rl[j] = f2bf(f - bf2f(h));
    }
    uint2 oh, ol;
    oh.x = rh[0] | (rh[1] << 16); oh.y = rh[2] | (rh[3] << 16);
    ol.x = rl[0] | (rl[1] << 16); ol.y = rl[2] | (rl[3] << 16);
    *reinterpret_cast<uint2*>(&dh[(size_t)(n0 + ty) * DD + k0 + tx]) = oh;
    *reinterpret_cast<uint2*>(&dl[(size_t)(n0 + ty) * DD + k0 + tx]) = ol;
}

// ---------------- Split bf16 MFMA GEMM + bias ----------------
// C[M,N] = (Ah+Al)[M,K] @ (Bh+Bl)[N,K]^T + b, terms AhBh + AlBh + AhBl (fp32 acc).
// out_bf16: 0 -> fp32 C, 1 -> bf16 C.
#define GBM 128
#define GBN 128
#define GBK 64
#define LDK 72   // +8 bf16 pad keeps frag-row reads 2-way (free)

__global__ __launch_bounds__(256) void gemm_mfma_split(const ushortT* __restrict__ Ah,
                                                       const ushortT* __restrict__ Al,
                                                       const ushortT* __restrict__ Bh,
                                                       const ushortT* __restrict__ Bl,
                                                       const float* __restrict__ bias,
                                                       void* __restrict__ Cout,
                                                       int M, int N, int K, int out_bf16) {
    __shared__ short Ash[GBM][LDK];
    __shared__ short Asl[GBM][LDK];
    __shared__ short Bsh[GBN][LDK];
    __shared__ short Bsl[GBN][LDK];
    const int tid = threadIdx.x;
    const int lane = tid & 63;
    const int wid = tid >> 6;
    const int bm = blockIdx.y * GBM;
    const int bn = blockIdx.x * GBN;
    const int wm = (wid >> 1) * 64;
    const int wn = (wid & 1) * 64;

    f32x4 acc[4][4];
    #pragma unroll
    for (int i = 0; i < 4; ++i)
        #pragma unroll
        for (int j = 0; j < 4; ++j)
            acc[i][j] = (f32x4){0.f, 0.f, 0.f, 0.f};

    const int srow = tid >> 3;
    const int schk = (tid & 7) * 8;
    const int fr = lane & 15;
    const int kg = (lane >> 4) * 8;

    for (int k0 = 0; k0 < K; k0 += GBK) {
        #pragma unroll
        for (int p = 0; p < 4; ++p) {
            const int r = srow + p * 32;
            const size_t ga = (size_t)(bm + r) * K + k0 + schk;
            const size_t gb = (size_t)(bn + r) * K + k0 + schk;
            *reinterpret_cast<bf16x8*>(&Ash[r][schk]) = *reinterpret_cast<const bf16x8*>(&Ah[ga]);
            *reinterpret_cast<bf16x8*>(&Asl[r][schk]) = *reinterpret_cast<const bf16x8*>(&Al[ga]);
            *reinterpret_cast<bf16x8*>(&Bsh[r][schk]) = *reinterpret_cast<const bf16x8*>(&Bh[gb]);
            *reinterpret_cast<bf16x8*>(&Bsl[r][schk]) = *reinterpret_cast<const bf16x8*>(&Bl[gb]);
        }
        __syncthreads();
        #pragma unroll
        for (int kk = 0; kk < 2; ++kk) {
            bf16x8 avh[4], avl[4], bvh[4], bvl[4];
            #pragma unroll
            for (int i = 0; i < 4; ++i) {
                avh[i] = *reinterpret_cast<const bf16x8*>(&Ash[wm + i * 16 + fr][kk * 32 + kg]);
                avl[i] = *reinterpret_cast<const bf16x8*>(&Asl[wm + i * 16 + fr][kk * 32 + kg]);
                bvh[i] = *reinterpret_cast<const bf16x8*>(&Bsh[wn + i * 16 + fr][kk * 32 + kg]);
                bvl[i] = *reinterpret_cast<const bf16x8*>(&Bsl[wn + i * 16 + fr][kk * 32 + kg]);
            }
            #pragma unroll
            for (int i = 0; i < 4; ++i)
                #pragma unroll
                for (int j = 0; j < 4; ++j) {
                    acc[i][j] = __builtin_amdgcn_mfma_f32_16x16x32_bf16(avh[i], bvh[j], acc[i][j], 0, 0, 0);
                    acc[i][j] = __builtin_amdgcn_mfma_f32_16x16x32_bf16(avl[i], bvh[j], acc[i][j], 0, 0, 0);
                    acc[i][j] = __builtin_amdgcn_mfma_f32_16x16x32_bf16(avh[i], bvl[j], acc[i][j], 0, 0, 0);
                }
        }
        __syncthreads();
    }

    const int fq = lane >> 4;
    #pragma unroll
    for (int j = 0; j < 4; ++j) {
        const int col = bn + wn + j * 16 + fr;
        const float bvv = bias[col];
        #pragma unroll
        for (int i = 0; i < 4; ++i) {
            const int row0 = bm + wm + i * 16 + fq * 4;
            #pragma unroll
            for (int r = 0; r < 4; ++r) {
                const float val = acc[i][j][r] + bvv;
                if (out_bf16) {
                    ((ushortT*)Cout)[(size_t)(row0 + r) * N + col] = (ushortT)f2bf(val);
                } else {
                    ((float*)Cout)[(size_t)(row0 + r) * N + col] = val;
                }
            }
        }
    }
}

// ---------------- Attention: one wave per (b,t), all 8 heads; V bf16; AO hi/lo ----------------
__global__ __launch_bounds__(256) void attn2_kernel(const float* __restrict__ Q,
                                                    const float* __restrict__ K,
                                                    const ushortT* __restrict__ V,
                                                    const int* __restrict__ kv_g,
                                                    const int* __restrict__ table,
                                                    const float* __restrict__ temp_ptr,
                                                    ushortT* __restrict__ AOh,
                                                    ushortT* __restrict__ AOl, int B) {
    const int lane = threadIdx.x & 63;
    const int u = (blockIdx.x * blockDim.x + threadIdx.x) >> 6;  // b*TT + t
    if (u >= B * TT) return;
    const int t = u & (TT - 1);
    const float scale_inv = 1.0f / (8.0f * fabsf(temp_ptr[0]));

    const int* rt = &table[kv_g[t] * WW];
    int sidx[WW];
    #pragma unroll
    for (int w = 0; w < WW; ++w) sidx[w] = rt[w];

    const size_t rowbase = (size_t)u * DD + lane * 8;
    const size_t bbase = (size_t)(u - t) * DD;
    const float4 q0 = *reinterpret_cast<const float4*>(&Q[rowbase]);
    const float4 q1 = *reinterpret_cast<const float4*>(&Q[rowbase + 4]);

    float sc[WW];
    #pragma unroll
    for (int w = 0; w < WW; ++w) {
        const float* kr = &K[bbase + (size_t)sidx[w] * DD + lane * 8];
        const float4 k0 = *reinterpret_cast<const float4*>(kr);
        const float4 k1 = *reinterpret_cast<const float4*>(kr + 4);
        float p = q0.x * k0.x + q0.y * k0.y + q0.z * k0.z + q0.w * k0.w
                + q1.x * k1.x + q1.y * k1.y + q1.z * k1.z + q1.w * k1.w;
        p += __shfl_xor(p, 1);
        p += __shfl_xor(p, 2);
        p += __shfl_xor(p, 4);
        sc[w] = p * scale_inv;
    }

    float m = sc[0];
    #pragma unroll
    for (int w = 1; w < WW; ++w) m = fmaxf(m, sc[w]);
    float pr[WW];
    float sum = 0.0f;
    #pragma unroll
    for (int w = 0; w < WW; ++w) { pr[w] = expf(sc[w] - m); sum += pr[w]; }
    const float inv = 1.0f / sum;

    float o[8] = {0.f, 0.f, 0.f, 0.f, 0.f, 0.f, 0.f, 0.f};
    #pragma unroll
    for (int w = 0; w < WW; ++w) {
        const uint4 vv = *reinterpret_cast<const uint4*>(&V[bbase + (size_t)sidx[w] * DD + lane * 8]);
        o[0] += pr[w] * bf2f(vv.x & 0xffffu); o[1] += pr[w] * bf2f(vv.x >> 16);
        o[2] += pr[w] * bf2f(vv.y & 0xffffu); o[3] += pr[w] * bf2f(vv.y >> 16);
        o[4] += pr[w] * bf2f(vv.z & 0xffffu); o[5] += pr[w] * bf2f(vv.z >> 16);
        o[6] += pr[w] * bf2f(vv.w & 0xffffu); o[7] += pr[w] * bf2f(vv.w >> 16);
    }
    uintT rh[8], rl[8];
    #pragma unroll
    for (int i = 0; i < 8; ++i) {
        const float val = o[i] * inv;
        uintT h = f2bf(val);
        rh[i] = h;
        rl[i] = f2bf(val - bf2f(h));
    }
    uint4 oh, ol;
    oh.x = rh[0] | (rh[1] << 16); oh.y = rh[2] | (rh[3] << 16);
    oh.z = rh[4] | (rh[5] << 16); oh.w = rh[6] | (rh[7] << 16);
    ol.x = rl[0] | (rl[1] << 16); ol.y = rl[2] | (rl[3] << 16);
    ol.z = rl[4] | (rl[5] << 16); ol.w = rl[6] | (rl[7] << 16);
    *reinterpret_cast<uint4*>(&AOh[rowbase]) = oh;
    *reinterpret_cast<uint4*>(&AOl[rowbase]) = ol;
}

// ---------------- Launcher ----------------
extern "C" void kernel_launch(void* const* d_in, const int* in_sizes, int n_in,
                              void* d_out, int out_size, void* d_ws, size_t ws_size,
                              hipStream_t stream) {
    const float* x    = (const float*)d_in[0];
    const float* Wq   = (const float*)d_in[1];
    const float* bq   = (const float*)d_in[2];
    const float* Wk   = (const float*)d_in[3];
    const float* bk   = (const float*)d_in[4];
    const float* Wv   = (const float*)d_in[5];
    const float* bv   = (const float*)d_in[6];
    const float* Wo   = (const float*)d_in[7];
    const float* bo   = (const float*)d_in[8];
    const float* temp = (const float*)d_in[9];
    float* out = (float*)d_out;

    const int B = in_sizes[0] / (TT * DD);   // 2
    const int M = B * TT;                    // 8192
    const size_t MD = (size_t)M * DD;

    float* Qb = (float*)d_ws;                          // fp32
    float* Kb = Qb + MD;                               // fp32
    ushortT* Vb = (ushortT*)(Kb + MD);                 // bf16
    ushortT* xh = Vb + MD;
    ushortT* xl = xh + MD;
    ushortT* Wqh = xl + MD;
    ushortT* Wql = Wqh + DD * DD;
    ushortT* Wkh = Wql + DD * DD;
    ushortT* Wkl = Wkh + DD * DD;
    ushortT* Wvh = Wkl + DD * DD;
    ushortT* Wvl = Wvh + DD * DD;
    ushortT* Woh = Wvl + DD * DD;
    ushortT* Wol = Woh + DD * DD;
    int* kvg   = (int*)(Wol + DD * DD);
    int* table = kvg + TT;
    ushortT* AOh = xh;   // x dead after V GEMM
    ushortT* AOl = xl;

    routes_table_kernel<<<1, 256, 0, stream>>>(kvg, table);
    convx_split_kernel<<<(int)(MD / 8 + 255) / 256, 256, 0, stream>>>(x, xh, xl, (int)(MD / 8));
    convw_split_kernel<<<dim3(16, 16, 4), 256, 0, stream>>>(Wq, Wk, Wv, Wo,
                                                            Wqh, Wql, Wkh, Wkl,
                                                            Wvh, Wvl, Woh, Wol);

    dim3 gg(DD / GBN, M / GBM);  // (4, 64)
    gemm_mfma_split<<<gg, 256, 0, stream>>>(xh, xl, Wqh, Wql, bq, Qb, M, DD, DD, 0);
    gemm_mfma_split<<<gg, 256, 0, stream>>>(xh, xl, Wkh, Wkl, bk, Kb, M, DD, DD, 0);
    gemm_mfma_split<<<gg, 256, 0, stream>>>(xh, xl, Wvh, Wvl, bv, Vb, M, DD, DD, 1);

    attn2_kernel<<<(B * TT * 64) / 256, 256, 0, stream>>>(Qb, Kb, Vb, kvg, table, temp, AOh, AOl, B);

    gemm_mfma_split<<<gg, 256, 0, stream>>>(AOh, AOl, Woh, Wol, bo, out, M, DD, DD, 0);
}

// Round 7
// 267.508 us; speedup vs baseline: 2.2011x; 1.7960x over previous
//
#include <hip/hip_runtime.h>
#include <hip/hip_bf16.h>
#include <cstdint>
#include <climits>

#define TT 4096
#define DD 512
#define HH 8
#define HD 64
#define WW 16
#define CDEPTH 8

typedef unsigned short ushortT;
typedef unsigned int uintT;
using bf16x8 = __attribute__((ext_vector_type(8))) short;
using f32x4  = __attribute__((ext_vector_type(4))) float;

static __device__ __forceinline__ uintT f2bf(float v) {
    __hip_bfloat16 h = __float2bfloat16(v);
    return (uintT)*reinterpret_cast<ushortT*>(&h);
}
static __device__ __forceinline__ float bf2f(uintT u) {
    return __uint_as_float(u << 16);
}

static __device__ __forceinline__ int cantor_m(int t) {
    float x = (float)t / (float)(TT - 1);
    x = fminf(fmaxf(x, 1e-6f), 1.0f - 1e-6f);
    int m = 0;
    #pragma unroll
    for (int i = 0; i < CDEPTH; ++i) {
        float x3 = x * 3.0f;
        float dg = floorf(x3);
        x = x3 - dg;
        m = (m << 1) | ((dg == 2.0f) ? 1 : 0);
    }
    return m;
}

// ---------------- Routes kernel A: per-bucket first-16 + counts (256 blocks) ----------------
// Block b: recompute all 4096 cantor values in LDS, histogram -> cnt of own bucket,
// first-16-by-index of own bucket via prefix scan. Also writes its 16-chunk of kv_g.
__global__ __launch_bounds__(256) void routes_f16_kernel(int* __restrict__ kv_g,
                                                         int* __restrict__ cnt_g,
                                                         int* __restrict__ f16_g) {
    __shared__ int kvloc[TT];
    __shared__ int pscan[256];
    const int tid = threadIdx.x;
    const int b = blockIdx.x;

    #pragma unroll
    for (int i = 0; i < 16; ++i) {
        const int t = i * 256 + tid;
        kvloc[t] = cantor_m(t);
    }
    __syncthreads();

    if (tid < 16) kv_g[b * 16 + tid] = kvloc[b * 16 + tid];

    // per-thread count of own-bucket matches in contiguous range [tid*16, tid*16+16)
    int localcnt = 0;
    #pragma unroll
    for (int i = 0; i < 16; ++i)
        localcnt += (kvloc[tid * 16 + i] == b) ? 1 : 0;

    // Hillis-Steele inclusive scan over 256 threads
    pscan[tid] = localcnt;
    __syncthreads();
    #pragma unroll
    for (int off = 1; off < 256; off <<= 1) {
        int v = (tid >= off) ? pscan[tid - off] : 0;
        __syncthreads();
        pscan[tid] += v;
        __syncthreads();
    }
    const int excl = pscan[tid] - localcnt;

    // second pass: write the first-16 slots
    int r = excl;
    #pragma unroll
    for (int i = 0; i < 16; ++i) {
        const int t = tid * 16 + i;
        if (kvloc[t] == b) {
            if (r < 16) f16_g[b * 16 + r] = t;
            ++r;
        }
    }
    if (tid == 255) cnt_g[b] = pscan[255];
}

// ---------------- Routes kernel B: ring-merge selection per bucket (1 block) ----------------
__global__ __launch_bounds__(256) void routes_merge_kernel(const int* __restrict__ cnt_g,
                                                           const int* __restrict__ f16_g,
                                                           int* __restrict__ table) {
    __shared__ int cnt[256];
    __shared__ int f16[256][16];
    const int tid = threadIdx.x;
    cnt[tid] = cnt_g[tid];
    {
        int4 a = reinterpret_cast<const int4*>(f16_g)[tid * 4 + 0];
        int4 b4 = reinterpret_cast<const int4*>(f16_g)[tid * 4 + 1];
        int4 c4 = reinterpret_cast<const int4*>(f16_g)[tid * 4 + 2];
        int4 d4 = reinterpret_cast<const int4*>(f16_g)[tid * 4 + 3];
        f16[tid][0] = a.x;  f16[tid][1] = a.y;  f16[tid][2] = a.z;  f16[tid][3] = a.w;
        f16[tid][4] = b4.x; f16[tid][5] = b4.y; f16[tid][6] = b4.z; f16[tid][7] = b4.w;
        f16[tid][8] = c4.x; f16[tid][9] = c4.y; f16[tid][10] = c4.z; f16[tid][11] = c4.w;
        f16[tid][12] = d4.x; f16[tid][13] = d4.y; f16[tid][14] = d4.z; f16[tid][15] = d4.w;
    }
    __syncthreads();

    int rtl[WW];
    int n = 0;
    {
        int c = cnt[tid];
        int take = (c < WW) ? c : WW;
        for (int i = 0; i < take; ++i) rtl[n++] = f16[tid][i];
    }
    for (int d = 1; n < WW && d <= 256; ++d) {
        const int lo = tid - d, hi = tid + d;
        const int clo = (lo >= 0) ? cnt[lo] : 0;
        const int chi = (hi < 256) ? cnt[hi] : 0;
        const int need = WW - n;
        if (clo + chi <= need) {
            for (int i = 0; i < clo; ++i) rtl[n++] = f16[lo][i];
            for (int i = 0; i < chi; ++i) rtl[n++] = f16[hi][i];
        } else {
            const int cl = (clo < WW) ? clo : WW;
            const int ch = (chi < WW) ? chi : WW;
            int i = 0, j = 0;
            while (n < WW) {
                int a = (i < cl) ? f16[lo][i] : INT_MAX;
                int b = (j < ch) ? f16[hi][j] : INT_MAX;
                if (a < b) { rtl[n++] = a; ++i; }
                else       { rtl[n++] = b; ++j; }
            }
        }
    }
    #pragma unroll
    for (int i = 0; i < WW; ++i) table[tid * WW + i] = rtl[i];
}

// ---------------- x -> bf16 hi/lo split ----------------
__global__ void convx_split_kernel(const float* __restrict__ in,
                                   ushortT* __restrict__ hi, ushortT* __restrict__ lo, int n8) {
    int i = blockIdx.x * blockDim.x + threadIdx.x;
    if (i >= n8) return;
    const float4 v0 = reinterpret_cast<const float4*>(in)[i * 2];
    const float4 v1 = reinterpret_cast<const float4*>(in)[i * 2 + 1];
    float v[8] = {v0.x, v0.y, v0.z, v0.w, v1.x, v1.y, v1.z, v1.w};
    uintT rh[8], rl[8];
    #pragma unroll
    for (int j = 0; j < 8; ++j) {
        uintT h = f2bf(v[j]);
        rh[j] = h;
        rl[j] = f2bf(v[j] - bf2f(h));
    }
    uint4 oh, ol;
    oh.x = rh[0] | (rh[1] << 16); oh.y = rh[2] | (rh[3] << 16);
    oh.z = rh[4] | (rh[5] << 16); oh.w = rh[6] | (rh[7] << 16);
    ol.x = rl[0] | (rl[1] << 16); ol.y = rl[2] | (rl[3] << 16);
    ol.z = rl[4] | (rl[5] << 16); ol.w = rl[6] | (rl[7] << 16);
    reinterpret_cast<uint4*>(hi)[i] = oh;
    reinterpret_cast<uint4*>(lo)[i] = ol;
}

// ---------------- W[k][n] -> Wt[n][k] bf16 hi/lo (4 weights) ----------------
__global__ __launch_bounds__(256) void convw_split_kernel(
        const float* __restrict__ W0, const float* __restrict__ W1,
        const float* __restrict__ W2, const float* __restrict__ W3,
        ushortT* __restrict__ H0, ushortT* __restrict__ L0,
        ushortT* __restrict__ H1, ushortT* __restrict__ L1,
        ushortT* __restrict__ H2, ushortT* __restrict__ L2,
        ushortT* __restrict__ H3, ushortT* __restrict__ L3) {
    const float* src; ushortT* dh; ushortT* dl;
    switch (blockIdx.z) {
        case 0: src = W0; dh = H0; dl = L0; break;
        case 1: src = W1; dh = H1; dl = L1; break;
        case 2: src = W2; dh = H2; dl = L2; break;
        default: src = W3; dh = H3; dl = L3; break;
    }
    __shared__ float tile[32][33];
    const int k0 = blockIdx.y * 32, n0 = blockIdx.x * 32;
    const int ty = threadIdx.x >> 3;
    const int tx = (threadIdx.x & 7) * 4;
    const float4 v = *reinterpret_cast<const float4*>(&src[(size_t)(k0 + ty) * DD + n0 + tx]);
    tile[ty][tx + 0] = v.x; tile[ty][tx + 1] = v.y; tile[ty][tx + 2] = v.z; tile[ty][tx + 3] = v.w;
    __syncthreads();
    uintT rh[4], rl[4];
    #pragma unroll
    for (int j = 0; j < 4; ++j) {
        float f = tile[tx + j][ty];
        uintT h = f2bf(f);
        rh[j] = h;
        rl[j] = f2bf(f - bf2f(h));
    }
    uint2 oh, ol;
    oh.x = rh[0] | (rh[1] << 16); oh.y = rh[2] | (rh[3] << 16);
    ol.x = rl[0] | (rl[1] << 16); ol.y = rl[2] | (rl[3] << 16);
    *reinterpret_cast<uint2*>(&dh[(size_t)(n0 + ty) * DD + k0 + tx]) = oh;
    *reinterpret_cast<uint2*>(&dl[(size_t)(n0 + ty) * DD + k0 + tx]) = ol;
}

// ---------------- Split bf16 MFMA GEMM + bias ----------------
// C[M,N] = (Ah+Al)[M,K] @ (Bh+Bl)[N,K]^T + b, terms AhBh + AlBh + AhBl (fp32 acc).
#define GBM 128
#define GBN 128
#define GBK 64
#define LDK 72   // +8 bf16 pad keeps frag-row reads 2-way (free)

__global__ __launch_bounds__(256) void gemm_mfma_split(const ushortT* __restrict__ Ah,
                                                       const ushortT* __restrict__ Al,
                                                       const ushortT* __restrict__ Bh,
                                                       const ushortT* __restrict__ Bl,
                                                       const float* __restrict__ bias,
                                                       void* __restrict__ Cout,
                                                       int M, int N, int K, int out_bf16) {
    __shared__ short Ash[GBM][LDK];
    __shared__ short Asl[GBM][LDK];
    __shared__ short Bsh[GBN][LDK];
    __shared__ short Bsl[GBN][LDK];
    const int tid = threadIdx.x;
    const int lane = tid & 63;
    const int wid = tid >> 6;
    const int bm = blockIdx.y * GBM;
    const int bn = blockIdx.x * GBN;
    const int wm = (wid >> 1) * 64;
    const int wn = (wid & 1) * 64;

    f32x4 acc[4][4];
    #pragma unroll
    for (int i = 0; i < 4; ++i)
        #pragma unroll
        for (int j = 0; j < 4; ++j)
            acc[i][j] = (f32x4){0.f, 0.f, 0.f, 0.f};

    const int srow = tid >> 3;
    const int schk = (tid & 7) * 8;
    const int fr = lane & 15;
    const int kg = (lane >> 4) * 8;

    for (int k0 = 0; k0 < K; k0 += GBK) {
        #pragma unroll
        for (int p = 0; p < 4; ++p) {
            const int r = srow + p * 32;
            const size_t ga = (size_t)(bm + r) * K + k0 + schk;
            const size_t gb = (size_t)(bn + r) * K + k0 + schk;
            *reinterpret_cast<bf16x8*>(&Ash[r][schk]) = *reinterpret_cast<const bf16x8*>(&Ah[ga]);
            *reinterpret_cast<bf16x8*>(&Asl[r][schk]) = *reinterpret_cast<const bf16x8*>(&Al[ga]);
            *reinterpret_cast<bf16x8*>(&Bsh[r][schk]) = *reinterpret_cast<const bf16x8*>(&Bh[gb]);
            *reinterpret_cast<bf16x8*>(&Bsl[r][schk]) = *reinterpret_cast<const bf16x8*>(&Bl[gb]);
        }
        __syncthreads();
        #pragma unroll
        for (int kk = 0; kk < 2; ++kk) {
            bf16x8 avh[4], avl[4], bvh[4], bvl[4];
            #pragma unroll
            for (int i = 0; i < 4; ++i) {
                avh[i] = *reinterpret_cast<const bf16x8*>(&Ash[wm + i * 16 + fr][kk * 32 + kg]);
                avl[i] = *reinterpret_cast<const bf16x8*>(&Asl[wm + i * 16 + fr][kk * 32 + kg]);
                bvh[i] = *reinterpret_cast<const bf16x8*>(&Bsh[wn + i * 16 + fr][kk * 32 + kg]);
                bvl[i] = *reinterpret_cast<const bf16x8*>(&Bsl[wn + i * 16 + fr][kk * 32 + kg]);
            }
            #pragma unroll
            for (int i = 0; i < 4; ++i)
                #pragma unroll
                for (int j = 0; j < 4; ++j) {
                    acc[i][j] = __builtin_amdgcn_mfma_f32_16x16x32_bf16(avh[i], bvh[j], acc[i][j], 0, 0, 0);
                    acc[i][j] = __builtin_amdgcn_mfma_f32_16x16x32_bf16(avl[i], bvh[j], acc[i][j], 0, 0, 0);
                    acc[i][j] = __builtin_amdgcn_mfma_f32_16x16x32_bf16(avh[i], bvl[j], acc[i][j], 0, 0, 0);
                }
        }
        __syncthreads();
    }

    const int fq = lane >> 4;
    #pragma unroll
    for (int j = 0; j < 4; ++j) {
        const int col = bn + wn + j * 16 + fr;
        const float bvv = bias[col];
        #pragma unroll
        for (int i = 0; i < 4; ++i) {
            const int row0 = bm + wm + i * 16 + fq * 4;
            #pragma unroll
            for (int r = 0; r < 4; ++r) {
                const float val = acc[i][j][r] + bvv;
                if (out_bf16) {
                    ((ushortT*)Cout)[(size_t)(row0 + r) * N + col] = (ushortT)f2bf(val);
                } else {
                    ((float*)Cout)[(size_t)(row0 + r) * N + col] = val;
                }
            }
        }
    }
}

// ---------------- Attention: one wave per (b,t), all 8 heads; V bf16; AO hi/lo ----------------
__global__ __launch_bounds__(256) void attn2_kernel(const float* __restrict__ Q,
                                                    const float* __restrict__ K,
                                                    const ushortT* __restrict__ V,
                                                    const int* __restrict__ kv_g,
                                                    const int* __restrict__ table,
                                                    const float* __restrict__ temp_ptr,
                                                    ushortT* __restrict__ AOh,
                                                    ushortT* __restrict__ AOl, int B) {
    const int lane = threadIdx.x & 63;
    const int u = (blockIdx.x * blockDim.x + threadIdx.x) >> 6;  // b*TT + t
    if (u >= B * TT) return;
    const int t = u & (TT - 1);
    const float scale_inv = 1.0f / (8.0f * fabsf(temp_ptr[0]));

    const int* rt = &table[kv_g[t] * WW];
    int sidx[WW];
    #pragma unroll
    for (int w = 0; w < WW; ++w) sidx[w] = rt[w];

    const size_t rowbase = (size_t)u * DD + lane * 8;
    const size_t bbase = (size_t)(u - t) * DD;
    const float4 q0 = *reinterpret_cast<const float4*>(&Q[rowbase]);
    const float4 q1 = *reinterpret_cast<const float4*>(&Q[rowbase + 4]);

    float sc[WW];
    #pragma unroll
    for (int w = 0; w < WW; ++w) {
        const float* kr = &K[bbase + (size_t)sidx[w] * DD + lane * 8];
        const float4 k0 = *reinterpret_cast<const float4*>(kr);
        const float4 k1 = *reinterpret_cast<const float4*>(kr + 4);
        float p = q0.x * k0.x + q0.y * k0.y + q0.z * k0.z + q0.w * k0.w
                + q1.x * k1.x + q1.y * k1.y + q1.z * k1.z + q1.w * k1.w;
        p += __shfl_xor(p, 1);
        p += __shfl_xor(p, 2);
        p += __shfl_xor(p, 4);
        sc[w] = p * scale_inv;
    }

    float m = sc[0];
    #pragma unroll
    for (int w = 1; w < WW; ++w) m = fmaxf(m, sc[w]);
    float pr[WW];
    float sum = 0.0f;
    #pragma unroll
    for (int w = 0; w < WW; ++w) { pr[w] = expf(sc[w] - m); sum += pr[w]; }
    const float inv = 1.0f / sum;

    float o[8] = {0.f, 0.f, 0.f, 0.f, 0.f, 0.f, 0.f, 0.f};
    #pragma unroll
    for (int w = 0; w < WW; ++w) {
        const uint4 vv = *reinterpret_cast<const uint4*>(&V[bbase + (size_t)sidx[w] * DD + lane * 8]);
        o[0] += pr[w] * bf2f(vv.x & 0xffffu); o[1] += pr[w] * bf2f(vv.x >> 16);
        o[2] += pr[w] * bf2f(vv.y & 0xffffu); o[3] += pr[w] * bf2f(vv.y >> 16);
        o[4] += pr[w] * bf2f(vv.z & 0xffffu); o[5] += pr[w] * bf2f(vv.z >> 16);
        o[6] += pr[w] * bf2f(vv.w & 0xffffu); o[7] += pr[w] * bf2f(vv.w >> 16);
    }
    uintT rh[8], rl[8];
    #pragma unroll
    for (int i = 0; i < 8; ++i) {
        const float val = o[i] * inv;
        uintT h = f2bf(val);
        rh[i] = h;
        rl[i] = f2bf(val - bf2f(h));
    }
    uint4 oh, ol;
    oh.x = rh[0] | (rh[1] << 16); oh.y = rh[2] | (rh[3] << 16);
    oh.z = rh[4] | (rh[5] << 16); oh.w = rh[6] | (rh[7] << 16);
    ol.x = rl[0] | (rl[1] << 16); ol.y = rl[2] | (rl[3] << 16);
    ol.z = rl[4] | (rl[5] << 16); ol.w = rl[6] | (rl[7] << 16);
    *reinterpret_cast<uint4*>(&AOh[rowbase]) = oh;
    *reinterpret_cast<uint4*>(&AOl[rowbase]) = ol;
}

// ---------------- Launcher ----------------
extern "C" void kernel_launch(void* const* d_in, const int* in_sizes, int n_in,
                              void* d_out, int out_size, void* d_ws, size_t ws_size,
                              hipStream_t stream) {
    const float* x    = (const float*)d_in[0];
    const float* Wq   = (const float*)d_in[1];
    const float* bq   = (const float*)d_in[2];
    const float* Wk   = (const float*)d_in[3];
    const float* bk   = (const float*)d_in[4];
    const float* Wv   = (const float*)d_in[5];
    const float* bv   = (const float*)d_in[6];
    const float* Wo   = (const float*)d_in[7];
    const float* bo   = (const float*)d_in[8];
    const float* temp = (const float*)d_in[9];
    float* out = (float*)d_out;

    const int B = in_sizes[0] / (TT * DD);   // 2
    const int M = B * TT;                    // 8192
    const size_t MD = (size_t)M * DD;

    float* Qb = (float*)d_ws;                          // fp32
    float* Kb = Qb + MD;                               // fp32
    ushortT* Vb = (ushortT*)(Kb + MD);                 // bf16
    ushortT* xh = Vb + MD;
    ushortT* xl = xh + MD;
    ushortT* Wqh = xl + MD;
    ushortT* Wql = Wqh + DD * DD;
    ushortT* Wkh = Wql + DD * DD;
    ushortT* Wkl = Wkh + DD * DD;
    ushortT* Wvh = Wkl + DD * DD;
    ushortT* Wvl = Wvh + DD * DD;
    ushortT* Woh = Wvl + DD * DD;
    ushortT* Wol = Woh + DD * DD;
    int* kvg   = (int*)(Wol + DD * DD);
    int* table = kvg + TT;
    int* cntg  = table + 256 * WW;
    int* f16g  = cntg + 256;
    ushortT* AOh = xh;   // x dead after V GEMM
    ushortT* AOl = xl;

    routes_f16_kernel<<<256, 256, 0, stream>>>(kvg, cntg, f16g);
    routes_merge_kernel<<<1, 256, 0, stream>>>(cntg, f16g, table);
    convx_split_kernel<<<(int)(MD / 8 + 255) / 256, 256, 0, stream>>>(x, xh, xl, (int)(MD / 8));
    convw_split_kernel<<<dim3(16, 16, 4), 256, 0, stream>>>(Wq, Wk, Wv, Wo,
                                                            Wqh, Wql, Wkh, Wkl,
                                                            Wvh, Wvl, Woh, Wol);

    dim3 gg(DD / GBN, M / GBM);  // (4, 64)
    gemm_mfma_split<<<gg, 256, 0, stream>>>(xh, xl, Wqh, Wql, bq, Qb, M, DD, DD, 0);
    gemm_mfma_split<<<gg, 256, 0, stream>>>(xh, xl, Wkh, Wkl, bk, Kb, M, DD, DD, 0);
    gemm_mfma_split<<<gg, 256, 0, stream>>>(xh, xl, Wvh, Wvl, bv, Vb, M, DD, DD, 1);

    attn2_kernel<<<(B * TT * 64) / 256, 256, 0, stream>>>(Qb, Kb, Vb, kvg, table, temp, AOh, AOl, B);

    gemm_mfma_split<<<gg, 256, 0, stream>>>(AOh, AOl, Woh, Wol, bo, out, M, DD, DD, 0);
}

// Round 8
// 150.131 us; speedup vs baseline: 3.9220x; 1.7818x over previous
//
#include <hip/hip_runtime.h>
#include <hip/hip_bf16.h>
#include <cstdint>
#include <climits>

#define TT 4096
#define DD 512
#define HH 8
#define HD 64
#define WW 16
#define CDEPTH 8

typedef unsigned short ushortT;
typedef unsigned int uintT;
using bf16x8 = __attribute__((ext_vector_type(8))) short;
using f32x4  = __attribute__((ext_vector_type(4))) float;

static __device__ __forceinline__ uintT f2bf(float v) {
    __hip_bfloat16 h = __float2bfloat16(v);
    return (uintT)*reinterpret_cast<ushortT*>(&h);
}
static __device__ __forceinline__ float bf2f(uintT u) {
    return __uint_as_float(u << 16);
}

static __device__ __forceinline__ int cantor_m(int t) {
    float x = (float)t / (float)(TT - 1);
    x = fminf(fmaxf(x, 1e-6f), 1.0f - 1e-6f);
    int m = 0;
    #pragma unroll
    for (int i = 0; i < CDEPTH; ++i) {
        float x3 = x * 3.0f;
        float dg = floorf(x3);
        x = x3 - dg;
        m = (m << 1) | ((dg == 2.0f) ? 1 : 0);
    }
    return m;
}

// ---------------- Routes kernel A: per-bucket first-16 + counts (256 blocks) ----------------
__global__ __launch_bounds__(256) void routes_f16_kernel(int* __restrict__ kv_g,
                                                         int* __restrict__ cnt_g,
                                                         int* __restrict__ f16_g) {
    __shared__ int kvloc[TT];
    __shared__ int pscan[256];
    const int tid = threadIdx.x;
    const int b = blockIdx.x;

    #pragma unroll
    for (int i = 0; i < 16; ++i) {
        const int t = i * 256 + tid;
        kvloc[t] = cantor_m(t);
    }
    __syncthreads();

    if (tid < 16) kv_g[b * 16 + tid] = kvloc[b * 16 + tid];

    int localcnt = 0;
    #pragma unroll
    for (int i = 0; i < 16; ++i)
        localcnt += (kvloc[tid * 16 + i] == b) ? 1 : 0;

    pscan[tid] = localcnt;
    __syncthreads();
    #pragma unroll
    for (int off = 1; off < 256; off <<= 1) {
        int v = (tid >= off) ? pscan[tid - off] : 0;
        __syncthreads();
        pscan[tid] += v;
        __syncthreads();
    }
    const int excl = pscan[tid] - localcnt;

    int r = excl;
    #pragma unroll
    for (int i = 0; i < 16; ++i) {
        const int t = tid * 16 + i;
        if (kvloc[t] == b) {
            if (r < 16) f16_g[b * 16 + r] = t;
            ++r;
        }
    }
    if (tid == 255) cnt_g[b] = pscan[255];
}

// ---------------- Routes kernel B: ring-merge selection per bucket (1 block) ----------------
__global__ __launch_bounds__(256) void routes_merge_kernel(const int* __restrict__ cnt_g,
                                                           const int* __restrict__ f16_g,
                                                           int* __restrict__ table) {
    __shared__ int cnt[256];
    __shared__ int f16[256][16];
    const int tid = threadIdx.x;
    cnt[tid] = cnt_g[tid];
    {
        int4 a = reinterpret_cast<const int4*>(f16_g)[tid * 4 + 0];
        int4 b4 = reinterpret_cast<const int4*>(f16_g)[tid * 4 + 1];
        int4 c4 = reinterpret_cast<const int4*>(f16_g)[tid * 4 + 2];
        int4 d4 = reinterpret_cast<const int4*>(f16_g)[tid * 4 + 3];
        f16[tid][0] = a.x;  f16[tid][1] = a.y;  f16[tid][2] = a.z;  f16[tid][3] = a.w;
        f16[tid][4] = b4.x; f16[tid][5] = b4.y; f16[tid][6] = b4.z; f16[tid][7] = b4.w;
        f16[tid][8] = c4.x; f16[tid][9] = c4.y; f16[tid][10] = c4.z; f16[tid][11] = c4.w;
        f16[tid][12] = d4.x; f16[tid][13] = d4.y; f16[tid][14] = d4.z; f16[tid][15] = d4.w;
    }
    __syncthreads();

    int rtl[WW];
    int n = 0;
    {
        int c = cnt[tid];
        int take = (c < WW) ? c : WW;
        for (int i = 0; i < take; ++i) rtl[n++] = f16[tid][i];
    }
    for (int d = 1; n < WW && d <= 256; ++d) {
        const int lo = tid - d, hi = tid + d;
        const int clo = (lo >= 0) ? cnt[lo] : 0;
        const int chi = (hi < 256) ? cnt[hi] : 0;
        const int need = WW - n;
        if (clo + chi <= need) {
            for (int i = 0; i < clo; ++i) rtl[n++] = f16[lo][i];
            for (int i = 0; i < chi; ++i) rtl[n++] = f16[hi][i];
        } else {
            const int cl = (clo < WW) ? clo : WW;
            const int ch = (chi < WW) ? chi : WW;
            int i = 0, j = 0;
            while (n < WW) {
                int a = (i < cl) ? f16[lo][i] : INT_MAX;
                int b = (j < ch) ? f16[hi][j] : INT_MAX;
                if (a < b) { rtl[n++] = a; ++i; }
                else       { rtl[n++] = b; ++j; }
            }
        }
    }
    #pragma unroll
    for (int i = 0; i < WW; ++i) table[tid * WW + i] = rtl[i];
}

// ---------------- W[k][n] -> Wt[n][k] bf16 hi/lo (4 weights) ----------------
__global__ __launch_bounds__(256) void convw_split_kernel(
        const float* __restrict__ W0, const float* __restrict__ W1,
        const float* __restrict__ W2, const float* __restrict__ W3,
        ushortT* __restrict__ H0, ushortT* __restrict__ L0,
        ushortT* __restrict__ H1, ushortT* __restrict__ L1,
        ushortT* __restrict__ H2, ushortT* __restrict__ L2,
        ushortT* __restrict__ H3, ushortT* __restrict__ L3) {
    const float* src; ushortT* dh; ushortT* dl;
    switch (blockIdx.z) {
        case 0: src = W0; dh = H0; dl = L0; break;
        case 1: src = W1; dh = H1; dl = L1; break;
        case 2: src = W2; dh = H2; dl = L2; break;
        default: src = W3; dh = H3; dl = L3; break;
    }
    __shared__ float tile[32][33];
    const int k0 = blockIdx.y * 32, n0 = blockIdx.x * 32;
    const int ty = threadIdx.x >> 3;
    const int tx = (threadIdx.x & 7) * 4;
    const float4 v = *reinterpret_cast<const float4*>(&src[(size_t)(k0 + ty) * DD + n0 + tx]);
    tile[ty][tx + 0] = v.x; tile[ty][tx + 1] = v.y; tile[ty][tx + 2] = v.z; tile[ty][tx + 3] = v.w;
    __syncthreads();
    uintT rh[4], rl[4];
    #pragma unroll
    for (int j = 0; j < 4; ++j) {
        float f = tile[tx + j][ty];
        uintT h = f2bf(f);
        rh[j] = h;
        rl[j] = f2bf(f - bf2f(h));
    }
    uint2 oh, ol;
    oh.x = rh[0] | (rh[1] << 16); oh.y = rh[2] | (rh[3] << 16);
    ol.x = rl[0] | (rl[1] << 16); ol.y = rl[2] | (rl[3] << 16);
    *reinterpret_cast<uint2*>(&dh[(size_t)(n0 + ty) * DD + k0 + tx]) = oh;
    *reinterpret_cast<uint2*>(&dl[(size_t)(n0 + ty) * DD + k0 + tx]) = ol;
}

// ---------------- Fused QKV GEMM: 64x128 tile, BK=32, split-bf16 3-term ----------------
// A = x fp32 (hi/lo split inline in staging). N=1536 logical; seg selects W/bias/output.
#define QBM 64
#define QBN 128
#define QBK 32
#define QLDK 40   // 32 + 8 bf16 pad

__global__ __launch_bounds__(256, 4) void qkv_gemm(const float* __restrict__ x,
        const ushortT* __restrict__ Wqh, const ushortT* __restrict__ Wql,
        const ushortT* __restrict__ Wkh, const ushortT* __restrict__ Wkl,
        const ushortT* __restrict__ Wvh, const ushortT* __restrict__ Wvl,
        const float* __restrict__ bq, const float* __restrict__ bk, const float* __restrict__ bv,
        float* __restrict__ Qo, float* __restrict__ Ko, ushortT* __restrict__ Vo, int M) {
    __shared__ short Ash[QBM][QLDK];
    __shared__ short Asl[QBM][QLDK];
    __shared__ short Bsh[QBN][QLDK];
    __shared__ short Bsl[QBN][QLDK];
    const int tid = threadIdx.x;
    const int lane = tid & 63;
    const int wid = tid >> 6;
    const int bm = blockIdx.y * QBM;
    const int bnG = blockIdx.x * QBN;       // 0..1535
    const int seg = bnG >> 9;               // 0=Q 1=K 2=V
    const int bn = bnG & 511;
    const ushortT* __restrict__ Bhp = (seg == 0) ? Wqh : (seg == 1) ? Wkh : Wvh;
    const ushortT* __restrict__ Blp = (seg == 0) ? Wql : (seg == 1) ? Wkl : Wvl;
    const float* __restrict__ bias = (seg == 0) ? bq : (seg == 1) ? bk : bv;

    const int wr = wid >> 1;                // 0..1 : 32-row slab
    const int wc = wid & 1;                 // 0..1 : 64-col slab

    f32x4 acc[2][4];
    #pragma unroll
    for (int i = 0; i < 2; ++i)
        #pragma unroll
        for (int j = 0; j < 4; ++j)
            acc[i][j] = (f32x4){0.f, 0.f, 0.f, 0.f};

    const int arow = tid >> 2;              // 0..63
    const int achk = (tid & 3) * 8;
    const int fr = lane & 15;
    const int kg = (lane >> 4) * 8;

    for (int k0 = 0; k0 < DD; k0 += QBK) {
        // A staging: fp32 -> hi/lo bf16 (identical arithmetic to convx_split)
        {
            const float* src = &x[(size_t)(bm + arow) * DD + k0 + achk];
            const float4 v0 = *reinterpret_cast<const float4*>(src);
            const float4 v1 = *reinterpret_cast<const float4*>(src + 4);
            const float vv[8] = {v0.x, v0.y, v0.z, v0.w, v1.x, v1.y, v1.z, v1.w};
            bf16x8 vh, vl;
            #pragma unroll
            for (int j = 0; j < 8; ++j) {
                uintT h = f2bf(vv[j]);
                vh[j] = (short)h;
                vl[j] = (short)f2bf(vv[j] - bf2f(h));
            }
            *reinterpret_cast<bf16x8*>(&Ash[arow][achk]) = vh;
            *reinterpret_cast<bf16x8*>(&Asl[arow][achk]) = vl;
        }
        // B staging: 128 rows x 32 k, 2 slots/thread
        #pragma unroll
        for (int s = 0; s < 2; ++s) {
            const int slot = tid + s * 256;
            const int br = slot >> 2;
            const int bchk = (slot & 3) * 8;
            const size_t g = (size_t)(bn + br) * DD + k0 + bchk;
            *reinterpret_cast<bf16x8*>(&Bsh[br][bchk]) = *reinterpret_cast<const bf16x8*>(&Bhp[g]);
            *reinterpret_cast<bf16x8*>(&Bsl[br][bchk]) = *reinterpret_cast<const bf16x8*>(&Blp[g]);
        }
        __syncthreads();
        {
            bf16x8 avh[2], avl[2], bvh[4], bvl[4];
            #pragma unroll
            for (int i = 0; i < 2; ++i) {
                avh[i] = *reinterpret_cast<const bf16x8*>(&Ash[wr * 32 + i * 16 + fr][kg]);
                avl[i] = *reinterpret_cast<const bf16x8*>(&Asl[wr * 32 + i * 16 + fr][kg]);
            }
            #pragma unroll
            for (int j = 0; j < 4; ++j) {
                bvh[j] = *reinterpret_cast<const bf16x8*>(&Bsh[wc * 64 + j * 16 + fr][kg]);
                bvl[j] = *reinterpret_cast<const bf16x8*>(&Bsl[wc * 64 + j * 16 + fr][kg]);
            }
            #pragma unroll
            for (int i = 0; i < 2; ++i)
                #pragma unroll
                for (int j = 0; j < 4; ++j) {
                    acc[i][j] = __builtin_amdgcn_mfma_f32_16x16x32_bf16(avh[i], bvh[j], acc[i][j], 0, 0, 0);
                    acc[i][j] = __builtin_amdgcn_mfma_f32_16x16x32_bf16(avl[i], bvh[j], acc[i][j], 0, 0, 0);
                    acc[i][j] = __builtin_amdgcn_mfma_f32_16x16x32_bf16(avh[i], bvl[j], acc[i][j], 0, 0, 0);
                }
        }
        __syncthreads();
    }

    const int fq = lane >> 4;
    #pragma unroll
    for (int j = 0; j < 4; ++j) {
        const int col = bn + wc * 64 + j * 16 + fr;
        const float bvv = bias[col];
        #pragma unroll
        for (int i = 0; i < 2; ++i) {
            const int row0 = bm + wr * 32 + i * 16 + fq * 4;
            #pragma unroll
            for (int r = 0; r < 4; ++r) {
                const float val = acc[i][j][r] + bvv;
                if (seg == 2) {
                    Vo[(size_t)(row0 + r) * DD + col] = (ushortT)f2bf(val);
                } else {
                    float* dst = seg ? Ko : Qo;
                    dst[(size_t)(row0 + r) * DD + col] = val;
                }
            }
        }
    }
}

// ---------------- Output GEMM: A = AO hi/lo bf16, B = Wo hi/lo, fp32 out + bias ----------------
__global__ __launch_bounds__(256, 4) void out_gemm(const ushortT* __restrict__ Ahg,
                                                   const ushortT* __restrict__ Alg,
                                                   const ushortT* __restrict__ Bh,
                                                   const ushortT* __restrict__ Bl,
                                                   const float* __restrict__ bias,
                                                   float* __restrict__ C, int M) {
    __shared__ short Ash[QBM][QLDK];
    __shared__ short Asl[QBM][QLDK];
    __shared__ short Bsh[QBN][QLDK];
    __shared__ short Bsl[QBN][QLDK];
    const int tid = threadIdx.x;
    const int lane = tid & 63;
    const int wid = tid >> 6;
    const int bm = blockIdx.y * QBM;
    const int bn = blockIdx.x * QBN;
    const int wr = wid >> 1;
    const int wc = wid & 1;

    f32x4 acc[2][4];
    #pragma unroll
    for (int i = 0; i < 2; ++i)
        #pragma unroll
        for (int j = 0; j < 4; ++j)
            acc[i][j] = (f32x4){0.f, 0.f, 0.f, 0.f};

    const int arow = tid >> 2;
    const int achk = (tid & 3) * 8;
    const int fr = lane & 15;
    const int kg = (lane >> 4) * 8;

    for (int k0 = 0; k0 < DD; k0 += QBK) {
        {
            const size_t g = (size_t)(bm + arow) * DD + k0 + achk;
            *reinterpret_cast<bf16x8*>(&Ash[arow][achk]) = *reinterpret_cast<const bf16x8*>(&Ahg[g]);
            *reinterpret_cast<bf16x8*>(&Asl[arow][achk]) = *reinterpret_cast<const bf16x8*>(&Alg[g]);
        }
        #pragma unroll
        for (int s = 0; s < 2; ++s) {
            const int slot = tid + s * 256;
            const int br = slot >> 2;
            const int bchk = (slot & 3) * 8;
            const size_t g = (size_t)(bn + br) * DD + k0 + bchk;
            *reinterpret_cast<bf16x8*>(&Bsh[br][bchk]) = *reinterpret_cast<const bf16x8*>(&Bh[g]);
            *reinterpret_cast<bf16x8*>(&Bsl[br][bchk]) = *reinterpret_cast<const bf16x8*>(&Bl[g]);
        }
        __syncthreads();
        {
            bf16x8 avh[2], avl[2], bvh[4], bvl[4];
            #pragma unroll
            for (int i = 0; i < 2; ++i) {
                avh[i] = *reinterpret_cast<const bf16x8*>(&Ash[wr * 32 + i * 16 + fr][kg]);
                avl[i] = *reinterpret_cast<const bf16x8*>(&Asl[wr * 32 + i * 16 + fr][kg]);
            }
            #pragma unroll
            for (int j = 0; j < 4; ++j) {
                bvh[j] = *reinterpret_cast<const bf16x8*>(&Bsh[wc * 64 + j * 16 + fr][kg]);
                bvl[j] = *reinterpret_cast<const bf16x8*>(&Bsl[wc * 64 + j * 16 + fr][kg]);
            }
            #pragma unroll
            for (int i = 0; i < 2; ++i)
                #pragma unroll
                for (int j = 0; j < 4; ++j) {
                    acc[i][j] = __builtin_amdgcn_mfma_f32_16x16x32_bf16(avh[i], bvh[j], acc[i][j], 0, 0, 0);
                    acc[i][j] = __builtin_amdgcn_mfma_f32_16x16x32_bf16(avl[i], bvh[j], acc[i][j], 0, 0, 0);
                    acc[i][j] = __builtin_amdgcn_mfma_f32_16x16x32_bf16(avh[i], bvl[j], acc[i][j], 0, 0, 0);
                }
        }
        __syncthreads();
    }

    const int fq = lane >> 4;
    #pragma unroll
    for (int j = 0; j < 4; ++j) {
        const int col = bn + wc * 64 + j * 16 + fr;
        const float bvv = bias[col];
        #pragma unroll
        for (int i = 0; i < 2; ++i) {
            const int row0 = bm + wr * 32 + i * 16 + fq * 4;
            #pragma unroll
            for (int r = 0; r < 4; ++r)
                C[(size_t)(row0 + r) * DD + col] = acc[i][j][r] + bvv;
        }
    }
}

// ---------------- Attention: one wave per (b,t), all 8 heads; V bf16; AO hi/lo ----------------
__global__ __launch_bounds__(256) void attn2_kernel(const float* __restrict__ Q,
                                                    const float* __restrict__ K,
                                                    const ushortT* __restrict__ V,
                                                    const int* __restrict__ kv_g,
                                                    const int* __restrict__ table,
                                                    const float* __restrict__ temp_ptr,
                                                    ushortT* __restrict__ AOh,
                                                    ushortT* __restrict__ AOl, int B) {
    const int lane = threadIdx.x & 63;
    const int u = (blockIdx.x * blockDim.x + threadIdx.x) >> 6;  // b*TT + t
    if (u >= B * TT) return;
    const int t = u & (TT - 1);
    const float scale_inv = 1.0f / (8.0f * fabsf(temp_ptr[0]));

    const int* rt = &table[kv_g[t] * WW];
    int sidx[WW];
    #pragma unroll
    for (int w = 0; w < WW; ++w) sidx[w] = rt[w];

    const size_t rowbase = (size_t)u * DD + lane * 8;
    const size_t bbase = (size_t)(u - t) * DD;
    const float4 q0 = *reinterpret_cast<const float4*>(&Q[rowbase]);
    const float4 q1 = *reinterpret_cast<const float4*>(&Q[rowbase + 4]);

    float sc[WW];
    #pragma unroll
    for (int w = 0; w < WW; ++w) {
        const float* kr = &K[bbase + (size_t)sidx[w] * DD + lane * 8];
        const float4 k0 = *reinterpret_cast<const float4*>(kr);
        const float4 k1 = *reinterpret_cast<const float4*>(kr + 4);
        float p = q0.x * k0.x + q0.y * k0.y + q0.z * k0.z + q0.w * k0.w
                + q1.x * k1.x + q1.y * k1.y + q1.z * k1.z + q1.w * k1.w;
        p += __shfl_xor(p, 1);
        p += __shfl_xor(p, 2);
        p += __shfl_xor(p, 4);
        sc[w] = p * scale_inv;
    }

    float m = sc[0];
    #pragma unroll
    for (int w = 1; w < WW; ++w) m = fmaxf(m, sc[w]);
    float pr[WW];
    float sum = 0.0f;
    #pragma unroll
    for (int w = 0; w < WW; ++w) { pr[w] = expf(sc[w] - m); sum += pr[w]; }
    const float inv = 1.0f / sum;

    float o[8] = {0.f, 0.f, 0.f, 0.f, 0.f, 0.f, 0.f, 0.f};
    #pragma unroll
    for (int w = 0; w < WW; ++w) {
        const uint4 vv = *reinterpret_cast<const uint4*>(&V[bbase + (size_t)sidx[w] * DD + lane * 8]);
        o[0] += pr[w] * bf2f(vv.x & 0xffffu); o[1] += pr[w] * bf2f(vv.x >> 16);
        o[2] += pr[w] * bf2f(vv.y & 0xffffu); o[3] += pr[w] * bf2f(vv.y >> 16);
        o[4] += pr[w] * bf2f(vv.z & 0xffffu); o[5] += pr[w] * bf2f(vv.z >> 16);
        o[6] += pr[w] * bf2f(vv.w & 0xffffu); o[7] += pr[w] * bf2f(vv.w >> 16);
    }
    uintT rh[8], rl[8];
    #pragma unroll
    for (int i = 0; i < 8; ++i) {
        const float val = o[i] * inv;
        uintT h = f2bf(val);
        rh[i] = h;
        rl[i] = f2bf(val - bf2f(h));
    }
    uint4 oh, ol;
    oh.x = rh[0] | (rh[1] << 16); oh.y = rh[2] | (rh[3] << 16);
    oh.z = rh[4] | (rh[5] << 16); oh.w = rh[6] | (rh[7] << 16);
    ol.x = rl[0] | (rl[1] << 16); ol.y = rl[2] | (rl[3] << 16);
    ol.z = rl[4] | (rl[5] << 16); ol.w = rl[6] | (rl[7] << 16);
    *reinterpret_cast<uint4*>(&AOh[rowbase]) = oh;
    *reinterpret_cast<uint4*>(&AOl[rowbase]) = ol;
}

// ---------------- Launcher ----------------
extern "C" void kernel_launch(void* const* d_in, const int* in_sizes, int n_in,
                              void* d_out, int out_size, void* d_ws, size_t ws_size,
                              hipStream_t stream) {
    const float* x    = (const float*)d_in[0];
    const float* Wq   = (const float*)d_in[1];
    const float* bq   = (const float*)d_in[2];
    const float* Wk   = (const float*)d_in[3];
    const float* bk   = (const float*)d_in[4];
    const float* Wv   = (const float*)d_in[5];
    const float* bv   = (const float*)d_in[6];
    const float* Wo   = (const float*)d_in[7];
    const float* bo   = (const float*)d_in[8];
    const float* temp = (const float*)d_in[9];
    float* out = (float*)d_out;

    const int B = in_sizes[0] / (TT * DD);   // 2
    const int M = B * TT;                    // 8192
    const size_t MD = (size_t)M * DD;

    float* Qb = (float*)d_ws;                          // fp32
    float* Kb = Qb + MD;                               // fp32
    ushortT* Vb = (ushortT*)(Kb + MD);                 // bf16
    ushortT* AOh = Vb + MD;
    ushortT* AOl = AOh + MD;
    ushortT* Wqh = AOl + MD;
    ushortT* Wql = Wqh + DD * DD;
    ushortT* Wkh = Wql + DD * DD;
    ushortT* Wkl = Wkh + DD * DD;
    ushortT* Wvh = Wkl + DD * DD;
    ushortT* Wvl = Wvh + DD * DD;
    ushortT* Woh = Wvl + DD * DD;
    ushortT* Wol = Woh + DD * DD;
    int* kvg   = (int*)(Wol + DD * DD);
    int* table = kvg + TT;
    int* cntg  = table + 256 * WW;
    int* f16g  = cntg + 256;

    routes_f16_kernel<<<256, 256, 0, stream>>>(kvg, cntg, f16g);
    routes_merge_kernel<<<1, 256, 0, stream>>>(cntg, f16g, table);
    convw_split_kernel<<<dim3(16, 16, 4), 256, 0, stream>>>(Wq, Wk, Wv, Wo,
                                                            Wqh, Wql, Wkh, Wkl,
                                                            Wvh, Wvl, Woh, Wol);

    dim3 qkvg(1536 / QBN, M / QBM);   // (12, 128)
    qkv_gemm<<<qkvg, 256, 0, stream>>>(x, Wqh, Wql, Wkh, Wkl, Wvh, Wvl,
                                       bq, bk, bv, Qb, Kb, Vb, M);

    attn2_kernel<<<(M * 64) / 256, 256, 0, stream>>>(Qb, Kb, Vb, kvg, table, temp, AOh, AOl, B);

    dim3 og(DD / QBN, M / QBM);       // (4, 128)
    out_gemm<<<og, 256, 0, stream>>>(AOh, AOl, Woh, Wol, bo, out, M);
}